// Round 16
// baseline (100.288 us; speedup 1.0000x reference)
//
#include <hip/hip_runtime.h>
#include <math.h>

typedef unsigned short u16;
typedef unsigned int u32;
typedef __attribute__((ext_vector_type(8))) short short8;   // 8 x bf16 (4 VGPRs)
typedef __attribute__((ext_vector_type(4))) float f32x4;
typedef __attribute__((ext_vector_type(2))) float f32x2;

#define NB 4
#define NH 56
#define NW 56
#define HW2 (NH*NW)          // 3136
#define NPIX (NB*HW2)        // 12544

// ---------- helpers ----------
__device__ __forceinline__ u16 f2b(float f) {           // f32 -> bf16 (RNE)
  union { float f; u32 u; } a; a.f = f;
  return (u16)((a.u + 0x7FFFu + ((a.u >> 16) & 1u)) >> 16);
}
__device__ __forceinline__ float b2f(u16 v) {
  union { u32 u; float f; } a; a.u = ((u32)v) << 16; return a.f;
}
__device__ __forceinline__ float gelu_exact(float v) {  // 0.5v(1+erf(v/sqrt2))
  return 0.5f * v * (1.0f + erff(v * 0.70710678118654752f));
}
// bijective XCD-contiguous chunk swizzle (m204 form)
__device__ __forceinline__ int xcd_swz(int bid, int nwg) {
  const int q = nwg >> 3, r = nwg & 7, x = bid & 7, j = bid >> 3;
  return (x < r ? x * (q + 1) : r * (q + 1) + (x - r) * q) + j;
}
// LDS swizzle for 512B-pitch bf16 rows: 16B unit b ^ low3(row)
__device__ __forceinline__ u32 swz(int r, int b) {
  return (u32)(r * 512 + ((b ^ (r & 7)) << 4));
}

// ============ D1: [prep weights (blocks 0..1456)] + [dwconv (1457..4592)] ============
__global__ __launch_bounds__(256) void k1_kernel(
    const float* __restrict__ w_in, const float* __restrict__ w_out,
    const float* __restrict__ w_fc1, const float* __restrict__ w_fc2,
    const float* __restrict__ w_off, const float* __restrict__ w_mask,
    const float* __restrict__ b_off, const float* __restrict__ b_mask,
    u16* __restrict__ wT, float* __restrict__ bias_cat,
    const float* __restrict__ xf, const float* __restrict__ wdw,
    const float* __restrict__ bdw, const float* __restrict__ lng,
    const float* __restrict__ lnb, u16* __restrict__ x1)
{
  const int blk = blockIdx.x, t = threadIdx.x;
  if (blk < 1456) {
    const float* src; int n, N;
    if      (blk < 256)  { src = w_in;   n = blk;        N = 256; }
    else if (blk < 512)  { src = w_out;  n = blk - 256;  N = 256; }
    else if (blk < 768)  { src = w_fc1;  n = blk - 512;  N = 256; }
    else if (blk < 1024) { src = w_fc2;  n = blk - 768;  N = 256; }
    else if (blk < 1312) { src = w_off;  n = blk - 1024; N = 288; }
    else                 { src = w_mask; n = blk - 1312; N = 144; }
    wT[blk * 256 + t] = f2b(src[t * N + n]);
  } else if (blk == 1456) {
    for (int j = t; j < 432; j += 256)
      bias_cat[j] = (j < 288) ? b_off[j] : b_mask[j - 288];
  } else {
    const int pb = xcd_swz(blk - 1457, 3136);
    const int p = pb * 4 + (t >> 6);      // wave-per-pixel, 4 px/block
    const int lane = t & 63, c0 = lane * 4;
    const int bb = p / HW2, hw = p - bb * HW2;
    const int h = hw / NW, w = hw - h * NW;
    float4 bd = *(const float4*)(bdw + c0);
    float a0 = bd.x, a1 = bd.y, a2 = bd.z, a3 = bd.w;
    #pragma unroll
    for (int kh = 0; kh < 3; ++kh) {
      const int hh = h + kh - 1;
      if ((unsigned)hh >= NH) continue;
      #pragma unroll
      for (int kw = 0; kw < 3; ++kw) {
        const int ww = w + kw - 1;
        if ((unsigned)ww >= NW) continue;
        float4 v = *(const float4*)(xf + (size_t)(bb * HW2 + hh * NW + ww) * 256 + c0);
        float4 wv = *(const float4*)(wdw + (kh * 3 + kw) * 256 + c0);
        a0 += v.x * wv.x; a1 += v.y * wv.y;
        a2 += v.z * wv.z; a3 += v.w * wv.w;
      }
    }
    float s1 = a0 + a1 + a2 + a3;
    float s2 = a0 * a0 + a1 * a1 + a2 * a2 + a3 * a3;
    #pragma unroll
    for (int d = 1; d < 64; d <<= 1) { s1 += __shfl_xor(s1, d); s2 += __shfl_xor(s2, d); }
    const float mu = s1 * (1.0f / 256.0f);
    const float var = s2 * (1.0f / 256.0f) - mu * mu;
    const float rs = rsqrtf(var + 1e-5f);
    float4 lg4 = *(const float4*)(lng + c0);
    float4 lb4 = *(const float4*)(lnb + c0);
    ushort4 o;
    o.x = f2b(gelu_exact((a0 - mu) * rs * lg4.x + lb4.x));
    o.y = f2b(gelu_exact((a1 - mu) * rs * lg4.y + lb4.y));
    o.z = f2b(gelu_exact((a2 - mu) * rs * lg4.z + lb4.z));
    o.w = f2b(gelu_exact((a3 - mu) * rs * lg4.w + lb4.w));
    *(ushort4*)(x1 + (size_t)p * 256 + c0) = o;
  }
}

// ============ shared 64x64 MFMA GEMM body (K=256), bf16 out (R12) ============
template<int AF32>
__device__ __forceinline__ void gemm64_body(
    const void* __restrict__ Asrc, const u16* __restrict__ Brows,
    const float* __restrict__ bias, u16* __restrict__ Cout,
    int Ntot, int m0, int n0, char* As, char* Bs, int t)
{
  if (AF32) {
    const int r = t >> 2;                 // 4 threads per 256-f32 row
    const float4* src = (const float4*)((const float*)Asrc + (size_t)(m0 + r) * 256);
    #pragma unroll
    for (int i = 0; i < 16; ++i) {        // 16 float4 per thread = 64 f4/row
      const int f4 = (t & 3) + i * 4;
      float4 v = src[f4];
      uint2 pk;
      pk.x = (u32)f2b(v.x) | ((u32)f2b(v.y) << 16);
      pk.y = (u32)f2b(v.z) | ((u32)f2b(v.w) << 16);
      *(uint2*)(As + swz(r, f4 >> 1) + (f4 & 1) * 8) = pk;
    }
  } else {
    const int r = t >> 2, c0 = t & 3;
    const u16* Ag = (const u16*)Asrc + (size_t)(m0 + r) * 256;
    #pragma unroll
    for (int i = 0; i < 8; ++i) {
      const int b = c0 + i * 4;
      *(uint4*)(As + swz(r, b)) = *(const uint4*)(Ag + b * 8);
    }
  }
  {
    const int r = t >> 2, c0 = t & 3;
    const int nrow = n0 + r;
    const u16* Bg = Brows + (size_t)nrow * 256;
    const bool bok = nrow < Ntot;
    #pragma unroll
    for (int i = 0; i < 8; ++i) {
      const int b = c0 + i * 4;
      uint4 bv = make_uint4(0u, 0u, 0u, 0u);
      if (bok) bv = *(const uint4*)(Bg + b * 8);
      *(uint4*)(Bs + swz(r, b)) = bv;
    }
  }
  __syncthreads();
  const int l = t & 63, w = t >> 6;
  const int wm = (w >> 1) << 5, wn = (w & 1) << 5;
  const int lr = l & 15, lk = l >> 4;
  const int ra0 = wm + lr, ra1 = wm + 16 + lr;
  const int rb0 = wn + lr, rb1 = wn + 16 + lr;
  f32x4 acc00 = {}, acc01 = {}, acc10 = {}, acc11 = {};
  #pragma unroll
  for (int ks = 0; ks < 8; ++ks) {
    const int bb = ks * 4 + lk;
    short8 a0 = *(const short8*)(As + swz(ra0, bb));
    short8 a1 = *(const short8*)(As + swz(ra1, bb));
    short8 b0 = *(const short8*)(Bs + swz(rb0, bb));
    short8 b1 = *(const short8*)(Bs + swz(rb1, bb));
    acc00 = __builtin_amdgcn_mfma_f32_16x16x32_bf16(a0, b0, acc00, 0, 0, 0);
    acc01 = __builtin_amdgcn_mfma_f32_16x16x32_bf16(a0, b1, acc01, 0, 0, 0);
    acc10 = __builtin_amdgcn_mfma_f32_16x16x32_bf16(a1, b0, acc10, 0, 0, 0);
    acc11 = __builtin_amdgcn_mfma_f32_16x16x32_bf16(a1, b1, acc11, 0, 0, 0);
  }
  const f32x4 accs[2][2] = {{acc00, acc01}, {acc10, acc11}};
  #pragma unroll
  for (int mi = 0; mi < 2; ++mi)
    #pragma unroll
    for (int ni = 0; ni < 2; ++ni) {
      const int col = n0 + wn + ni * 16 + lr;
      if (col < Ntot) {
        const float bv = bias[col];
        #pragma unroll
        for (int r4 = 0; r4 < 4; ++r4) {
          const int row = m0 + wm + mi * 16 + lk * 4 + r4;
          Cout[(size_t)row * Ntot + col] = f2b(accs[mi][ni][r4] + bv);
        }
      }
    }
}

// ============ D2 (R12): [xp GEMM (blocks 0..783)] + [om GEMM (784..2155)] ============
__global__ __launch_bounds__(256) void k2_kernel(
    const float* __restrict__ xf, const u16* __restrict__ x1,
    const u16* __restrict__ wT, const float* __restrict__ b_in,
    const float* __restrict__ bcat, u16* __restrict__ xp_bf,
    u16* __restrict__ omb)
{
  __shared__ u16 lds[32768];              // 64 KB: A 32K | B 32K
  char* As = (char*)lds;
  char* Bs = (char*)(lds + 16384);
  const int t = threadIdx.x;
  if (blockIdx.x < 784) {
    const int sb = xcd_swz(blockIdx.x, 784);
    const int m0 = (sb >> 2) * 64, n0 = (sb & 3) * 64;
    gemm64_body<1>(xf, wT, b_in, xp_bf, 256, m0, n0, As, Bs, t);
  } else {
    const int sb = xcd_swz((int)blockIdx.x - 784, 1372);
    const int m0 = (sb / 7) * 64, n0 = (sb % 7) * 64;
    gemm64_body<0>(x1, wT + 1024 * 256, bcat, omb, 432, m0, n0, As, Bs, t);
  }
}

// ============ D3 fused: dcnv3 gather (32 px) -> w_out+LN1+res -> fc1+gelu ->
//              fc2 -> LN2+res.  BM=32, 512 thr, 392 blocks.
//              R12 base + (a) f32x2 packed gather FMA, (b) GEMM1 B-prefetch.
__global__ __launch_bounds__(512) void dcn_tail_kernel(
    const u16* __restrict__ xp, const u16* __restrict__ omb,
    const u16* __restrict__ wT, const float* __restrict__ x,
    const float* __restrict__ b_out, const float* __restrict__ gamma1,
    const float* __restrict__ ln1g, const float* __restrict__ ln1b,
    const float* __restrict__ b_fc1, const float* __restrict__ b_fc2,
    const float* __restrict__ gamma2, const float* __restrict__ ln2g,
    const float* __restrict__ ln2b, float* __restrict__ out)
{
  __shared__ u16 As[32 * 256];            // 16 KB, reused: y, x2b, m1 (swizzled rows)
  __shared__ u16 lom[32 * 432];           // 27648 B
  __shared__ float redS[32][8], redQ[32][8];
  const int t = threadIdx.x;
  const int blk = xcd_swz(blockIdx.x, 392);
  const int p0 = blk * 32;
  const int l = t & 63, w8 = t >> 6;      // phase-B wave/lane decomposition
  const int lr = l & 15, lk = l >> 4;
  const int colb = w8 * 32 + lr;

  // stage om rows (32 x 54 uint4)
  for (int i = t; i < 1728; i += 512) {
    const int row = i / 54, u = i - row * 54;
    *(uint4*)(lom + row * 432 + u * 8) =
        *(const uint4*)(omb + (size_t)(p0 + row) * 432 + u * 8);
  }
  __syncthreads();

  // prefetch GEMM1 (w_out) B fragments into registers: latency hides under gather
  short8 bpre0[8], bpre1[8];
  {
    const u16* Bb = wT + 256 * 256 + (size_t)colb * 256 + lk * 8;
    #pragma unroll
    for (int ks = 0; ks < 8; ++ks) {
      bpre0[ks] = *(const short8*)(Bb + ks * 32);
      bpre1[ks] = *(const short8*)(Bb + 16 * 256 + ks * 32);
    }
  }

  // ---- phase A: dcnv3 gather, 16 thr/px x 16 ch (packed f32x2 FMA) ----
  {
    const int lp = t >> 4, g = t & 15;
    const int p = p0 + lp;
    const int bb = p / HW2, hw = p - bb * HW2;
    const int h = hw / NW, w = hw - h * NW;
    const u16* off = lom + lp * 432 + g * 18;
    const u16* mk  = lom + lp * 432 + 288 + g * 9;
    float lg[9];
    float mx = -1e30f;
    #pragma unroll
    for (int k = 0; k < 9; ++k) { lg[k] = b2f(mk[k]); mx = fmaxf(mx, lg[k]); }
    float se = 0.0f;
    #pragma unroll
    for (int k = 0; k < 9; ++k) { lg[k] = __expf(lg[k] - mx); se += lg[k]; }
    const float inv = 1.0f / se;
    f32x2 a2[8];
    #pragma unroll
    for (int j = 0; j < 8; ++j) a2[j] = (f32x2){0.f, 0.f};
    const u16* gbase = xp + (size_t)bb * HW2 * 256 + g * 16;
    auto corner = [&](int cx, int cy, float wt) {
      if (cx < 0 || cx >= NW || cy < 0 || cy >= NH) return;
      const u16* vp = gbase + (size_t)(cy * NW + cx) * 256;
      uint4 v0 = *(const uint4*)vp;
      uint4 v1 = *(const uint4*)(vp + 8);
      const u32 wv[8] = {v0.x, v0.y, v0.z, v0.w, v1.x, v1.y, v1.z, v1.w};
      const f32x2 wt2 = (f32x2){wt, wt};
      #pragma unroll
      for (int j = 0; j < 8; ++j) {       // lo/hi bf16 pair -> packed f32 FMA
        union { u32 u; float f; } lo, hi;
        lo.u = wv[j] << 16; hi.u = wv[j] & 0xffff0000u;
        f32x2 v2; v2.x = lo.f; v2.y = hi.f;
        a2[j] += wt2 * v2;
      }
    };
    #pragma unroll
    for (int k = 0; k < 9; ++k) {
      const float px = (float)(w + (k % 3) - 1) + b2f(off[2 * k]);
      const float py = (float)(h + (k / 3) - 1) + b2f(off[2 * k + 1]);
      const float fx = floorf(px), fy = floorf(py);
      const int ix = (int)fx, iy = (int)fy;
      const float ax = px - fx, ay = py - fy;
      const float mwt = lg[k] * inv;
      corner(ix,     iy,     (1.0f - ax) * (1.0f - ay) * mwt);
      corner(ix + 1, iy,     ax * (1.0f - ay) * mwt);
      corner(ix,     iy + 1, (1.0f - ax) * ay * mwt);
      corner(ix + 1, iy + 1, ax * ay * mwt);
    }
    u16 tmp[16];
    #pragma unroll
    for (int j = 0; j < 8; ++j) {
      tmp[2 * j]     = f2b(a2[j].x);
      tmp[2 * j + 1] = f2b(a2[j].y);
    }
    const int u0 = g * 2;                 // 16B-unit indices u0, u0+1 of row lp
    *(uint4*)((char*)As + lp * 512 + (((u0    ) ^ (lp & 7)) << 4)) = *(const uint4*)(tmp);
    *(uint4*)((char*)As + lp * 512 + (((u0 + 1) ^ (lp & 7)) << 4)) = *(const uint4*)(tmp + 8);
  }
  __syncthreads();

  // ---- phase B: tail chain, BM=32, 8 waves x 32 cols ----
  f32x4 acc[2][2];
  auto do_gemm = [&](const u16* Bt) {
    #pragma unroll
    for (int mi = 0; mi < 2; ++mi)
      #pragma unroll
      for (int ni = 0; ni < 2; ++ni) acc[mi][ni] = (f32x4){0.f, 0.f, 0.f, 0.f};
    const u16* Bbase = Bt + (size_t)colb * 256 + lk * 8;
    #pragma unroll
    for (int ks = 0; ks < 8; ++ks) {
      short8 a0 = *(const short8*)((char*)As + swz(lr,      ks * 4 + lk));
      short8 a1 = *(const short8*)((char*)As + swz(16 + lr, ks * 4 + lk));
      #pragma unroll
      for (int ni = 0; ni < 2; ++ni) {
        short8 b = *(const short8*)(Bbase + ni * 16 * 256 + ks * 32);
        acc[0][ni] = __builtin_amdgcn_mfma_f32_16x16x32_bf16(a0, b, acc[0][ni], 0, 0, 0);
        acc[1][ni] = __builtin_amdgcn_mfma_f32_16x16x32_bf16(a1, b, acc[1][ni], 0, 0, 0);
      }
    }
  };
  auto lds_write_b16 = [&](int row, int col, u16 v) {
    *(u16*)((char*)As + row * 512 + (((col >> 3) ^ (row & 7)) << 4) + (col & 7) * 2) = v;
  };
  auto ln_reduce = [&](const float bv[2]) {
    float s1[2][4], s2[2][4];
    #pragma unroll
    for (int mi = 0; mi < 2; ++mi)
      #pragma unroll
      for (int r4 = 0; r4 < 4; ++r4) {
        float s = 0.f, q = 0.f;
        #pragma unroll
        for (int ni = 0; ni < 2; ++ni) {
          const float v = acc[mi][ni][r4] + bv[ni];
          s += v; q += v * v;
        }
        s1[mi][r4] = s; s2[mi][r4] = q;
      }
    #pragma unroll
    for (int d = 1; d < 16; d <<= 1)
      #pragma unroll
      for (int mi = 0; mi < 2; ++mi)
        #pragma unroll
        for (int r4 = 0; r4 < 4; ++r4) {
          s1[mi][r4] += __shfl_xor(s1[mi][r4], d);
          s2[mi][r4] += __shfl_xor(s2[mi][r4], d);
        }
    if (lr == 0) {
      #pragma unroll
      for (int mi = 0; mi < 2; ++mi)
        #pragma unroll
        for (int r4 = 0; r4 < 4; ++r4) {
          const int rl = mi * 16 + lk * 4 + r4;
          redS[rl][w8] = s1[mi][r4];
          redQ[rl][w8] = s2[mi][r4];
        }
    }
    __syncthreads();
  };
  auto row_stats = [&](int rl, float& mu, float& rs) {
    float S = 0.f, Q = 0.f;
    #pragma unroll
    for (int j = 0; j < 8; ++j) { S += redS[rl][j]; Q += redQ[rl][j]; }
    mu = S * (1.0f / 256.0f);
    const float var = Q * (1.0f / 256.0f) - mu * mu;
    rs = rsqrtf(var + 1e-5f);
  };

  // ---- GEMM1: y @ w_out (B from prefetched registers) ----
  {
    #pragma unroll
    for (int mi = 0; mi < 2; ++mi)
      #pragma unroll
      for (int ni = 0; ni < 2; ++ni) acc[mi][ni] = (f32x4){0.f, 0.f, 0.f, 0.f};
    #pragma unroll
    for (int ks = 0; ks < 8; ++ks) {
      short8 a0 = *(const short8*)((char*)As + swz(lr,      ks * 4 + lk));
      short8 a1 = *(const short8*)((char*)As + swz(16 + lr, ks * 4 + lk));
      acc[0][0] = __builtin_amdgcn_mfma_f32_16x16x32_bf16(a0, bpre0[ks], acc[0][0], 0, 0, 0);
      acc[1][0] = __builtin_amdgcn_mfma_f32_16x16x32_bf16(a1, bpre0[ks], acc[1][0], 0, 0, 0);
      acc[0][1] = __builtin_amdgcn_mfma_f32_16x16x32_bf16(a0, bpre1[ks], acc[0][1], 0, 0, 0);
      acc[1][1] = __builtin_amdgcn_mfma_f32_16x16x32_bf16(a1, bpre1[ks], acc[1][1], 0, 0, 0);
    }
  }
  float bv1[2] = {b_out[colb], b_out[colb + 16]};
  ln_reduce(bv1);                         // barrier inside (fences As reads)

  // ---- LN1 + residual -> x2 (regs) + x2b (LDS) ----
  float x2r[2][4][2];
  {
    const float gm[2]  = {gamma1[colb], gamma1[colb + 16]};
    const float lgv[2] = {ln1g[colb],   ln1g[colb + 16]};
    const float lbv[2] = {ln1b[colb],   ln1b[colb + 16]};
    #pragma unroll
    for (int mi = 0; mi < 2; ++mi)
      #pragma unroll
      for (int r4 = 0; r4 < 4; ++r4) {
        const int rl = mi * 16 + lk * 4 + r4;
        float mu, rs; row_stats(rl, mu, rs);
        const int row = p0 + rl;
        #pragma unroll
        for (int ni = 0; ni < 2; ++ni) {
          const float v = acc[mi][ni][r4] + bv1[ni];
          const float o = x[(size_t)row * 256 + colb + ni * 16]
                        + gm[ni] * ((v - mu) * rs * lgv[ni] + lbv[ni]);
          x2r[mi][r4][ni] = o;
          lds_write_b16(rl, colb + ni * 16, f2b(o));
        }
      }
  }
  __syncthreads();

  // ---- GEMM2: x2 @ w_fc1, gelu -> m1 (LDS) ----
  do_gemm(wT + 512 * 256);
  float m1v[2][4][2];
  const float bf1[2] = {b_fc1[colb], b_fc1[colb + 16]};
  #pragma unroll
  for (int mi = 0; mi < 2; ++mi)
    #pragma unroll
    for (int r4 = 0; r4 < 4; ++r4)
      #pragma unroll
      for (int ni = 0; ni < 2; ++ni)
        m1v[mi][r4][ni] = gelu_exact(acc[mi][ni][r4] + bf1[ni]);
  __syncthreads();                        // all GEMM2 As-reads done
  #pragma unroll
  for (int mi = 0; mi < 2; ++mi)
    #pragma unroll
    for (int r4 = 0; r4 < 4; ++r4) {
      const int rl = mi * 16 + lk * 4 + r4;
      #pragma unroll
      for (int ni = 0; ni < 2; ++ni)
        lds_write_b16(rl, colb + ni * 16, f2b(m1v[mi][r4][ni]));
    }
  __syncthreads();

  // ---- GEMM3: m1 @ w_fc2, LN2 + residual -> out ----
  do_gemm(wT + 768 * 256);
  float bv3[2] = {b_fc2[colb], b_fc2[colb + 16]};
  ln_reduce(bv3);
  {
    const float gm[2]  = {gamma2[colb], gamma2[colb + 16]};
    const float lgv[2] = {ln2g[colb],   ln2g[colb + 16]};
    const float lbv[2] = {ln2b[colb],   ln2b[colb + 16]};
    #pragma unroll
    for (int mi = 0; mi < 2; ++mi)
      #pragma unroll
      for (int r4 = 0; r4 < 4; ++r4) {
        const int rl = mi * 16 + lk * 4 + r4;
        float mu, rs; row_stats(rl, mu, rs);
        const int row = p0 + rl;
        #pragma unroll
        for (int ni = 0; ni < 2; ++ni) {
          const float v = acc[mi][ni][r4] + bv3[ni];
          out[(size_t)row * 256 + colb + ni * 16] =
              x2r[mi][r4][ni] + gm[ni] * ((v - mu) * rs * lgv[ni] + lbv[ni]);
        }
      }
  }
}

// ============ workspace layout (bytes) ============
static constexpr size_t OFF_WT  = 0;                    // 1456*256*2 = 745,472
static constexpr size_t OFF_BC  = 745472;               // 432*4, padded to 2048
static constexpr size_t OFF_XP  = 747520;               // xp bf16 (6,422,528)
static constexpr size_t OFF_X1  = 7170048;              // x1 bf16 (6,422,528)
static constexpr size_t OFF_OMB = 13592576;             // om bf16 NPIX*432*2 = 10,838,016
// total: 24,430,592 bytes

extern "C" void kernel_launch(void* const* d_in, const int* in_sizes, int n_in,
                              void* d_out, int out_size, void* d_ws, size_t ws_size,
                              hipStream_t stream)
{
  const float* x      = (const float*)d_in[0];
  const float* w_in   = (const float*)d_in[1];
  const float* b_in   = (const float*)d_in[2];
  const float* w_dw   = (const float*)d_in[3];
  const float* b_dw   = (const float*)d_in[4];
  const float* ln_dw_g= (const float*)d_in[5];
  const float* ln_dw_b= (const float*)d_in[6];
  const float* w_off  = (const float*)d_in[7];
  const float* b_off  = (const float*)d_in[8];
  const float* w_mask = (const float*)d_in[9];
  const float* b_mask = (const float*)d_in[10];
  const float* w_out  = (const float*)d_in[11];
  const float* b_out  = (const float*)d_in[12];
  const float* ln1_g  = (const float*)d_in[13];
  const float* ln1_b  = (const float*)d_in[14];
  const float* w_fc1  = (const float*)d_in[15];
  const float* b_fc1  = (const float*)d_in[16];
  const float* w_fc2  = (const float*)d_in[17];
  const float* b_fc2  = (const float*)d_in[18];
  const float* ln2_g  = (const float*)d_in[19];
  const float* ln2_b  = (const float*)d_in[20];
  const float* gamma1 = (const float*)d_in[21];
  const float* gamma2 = (const float*)d_in[22];
  float* out = (float*)d_out;

  char* ws = (char*)d_ws;
  u16*   wT    = (u16*)  (ws + OFF_WT);
  float* bcat  = (float*)(ws + OFF_BC);
  u16*   xp_bf = (u16*)  (ws + OFF_XP);
  u16*   x1    = (u16*)  (ws + OFF_X1);
  u16*   omb   = (u16*)  (ws + OFF_OMB);

  // D1: [prep weights + bias] || [dwconv+LN+GELU -> x1]
  k1_kernel<<<dim3(1457 + 3136), 256, 0, stream>>>(
      w_in, w_out, w_fc1, w_fc2, w_off, w_mask, b_off, b_mask, wT, bcat,
      x, w_dw, b_dw, ln_dw_g, ln_dw_b, x1);
  // D2 (R12): [xp GEMM 784 blocks] || [om GEMM 1372 blocks], 256 thr
  k2_kernel<<<dim3(784 + 1372), 256, 0, stream>>>(
      x, x1, wT, b_in, bcat, xp_bf, omb);
  // D3: fused dcnv3 gather + full tail -> out (R12 config + pk-fma + B-prefetch)
  dcn_tail_kernel<<<dim3(392), 512, 0, stream>>>(
      xp_bf, omb, wT, x, b_out, gamma1, ln1_g, ln1_b, b_fc1, b_fc2,
      gamma2, ln2_g, ln2_b, out);
}

// Round 17
// 87.937 us; speedup vs baseline: 1.1404x; 1.1404x over previous
//
#include <hip/hip_runtime.h>
#include <math.h>

typedef unsigned short u16;
typedef unsigned int u32;
typedef __attribute__((ext_vector_type(8))) short short8;   // 8 x bf16 (4 VGPRs)
typedef __attribute__((ext_vector_type(4))) float f32x4;

#define NB 4
#define NH 56
#define NW 56
#define HW2 (NH*NW)          // 3136
#define NPIX (NB*HW2)        // 12544

// ---------- helpers ----------
__device__ __forceinline__ u16 f2b(float f) {           // f32 -> bf16 (RNE)
  union { float f; u32 u; } a; a.f = f;
  return (u16)((a.u + 0x7FFFu + ((a.u >> 16) & 1u)) >> 16);
}
__device__ __forceinline__ float b2f(u16 v) {
  union { u32 u; float f; } a; a.u = ((u32)v) << 16; return a.f;
}
__device__ __forceinline__ float gelu_exact(float v) {  // 0.5v(1+erf(v/sqrt2))
  return 0.5f * v * (1.0f + erff(v * 0.70710678118654752f));
}
// bijective XCD-contiguous chunk swizzle (m204 form)
__device__ __forceinline__ int xcd_swz(int bid, int nwg) {
  const int q = nwg >> 3, r = nwg & 7, x = bid & 7, j = bid >> 3;
  return (x < r ? x * (q + 1) : r * (q + 1) + (x - r) * q) + j;
}
// LDS swizzle for 512B-pitch bf16 rows: 16B unit b ^ low3(row)
__device__ __forceinline__ u32 swz(int r, int b) {
  return (u32)(r * 512 + ((b ^ (r & 7)) << 4));
}

// ============ D1: [prep weights (blocks 0..1456)] + [dwconv (1457..4592)] ============
__global__ __launch_bounds__(256) void k1_kernel(
    const float* __restrict__ w_in, const float* __restrict__ w_out,
    const float* __restrict__ w_fc1, const float* __restrict__ w_fc2,
    const float* __restrict__ w_off, const float* __restrict__ w_mask,
    const float* __restrict__ b_off, const float* __restrict__ b_mask,
    u16* __restrict__ wT, float* __restrict__ bias_cat,
    const float* __restrict__ xf, const float* __restrict__ wdw,
    const float* __restrict__ bdw, const float* __restrict__ lng,
    const float* __restrict__ lnb, u16* __restrict__ x1)
{
  const int blk = blockIdx.x, t = threadIdx.x;
  if (blk < 1456) {
    const float* src; int n, N;
    if      (blk < 256)  { src = w_in;   n = blk;        N = 256; }
    else if (blk < 512)  { src = w_out;  n = blk - 256;  N = 256; }
    else if (blk < 768)  { src = w_fc1;  n = blk - 512;  N = 256; }
    else if (blk < 1024) { src = w_fc2;  n = blk - 768;  N = 256; }
    else if (blk < 1312) { src = w_off;  n = blk - 1024; N = 288; }
    else                 { src = w_mask; n = blk - 1312; N = 144; }
    wT[blk * 256 + t] = f2b(src[t * N + n]);
  } else if (blk == 1456) {
    for (int j = t; j < 432; j += 256)
      bias_cat[j] = (j < 288) ? b_off[j] : b_mask[j - 288];
  } else {
    const int pb = xcd_swz(blk - 1457, 3136);
    const int p = pb * 4 + (t >> 6);      // wave-per-pixel, 4 px/block
    const int lane = t & 63, c0 = lane * 4;
    const int bb = p / HW2, hw = p - bb * HW2;
    const int h = hw / NW, w = hw - h * NW;
    float4 bd = *(const float4*)(bdw + c0);
    float a0 = bd.x, a1 = bd.y, a2 = bd.z, a3 = bd.w;
    #pragma unroll
    for (int kh = 0; kh < 3; ++kh) {
      const int hh = h + kh - 1;
      if ((unsigned)hh >= NH) continue;
      #pragma unroll
      for (int kw = 0; kw < 3; ++kw) {
        const int ww = w + kw - 1;
        if ((unsigned)ww >= NW) continue;
        float4 v = *(const float4*)(xf + (size_t)(bb * HW2 + hh * NW + ww) * 256 + c0);
        float4 wv = *(const float4*)(wdw + (kh * 3 + kw) * 256 + c0);
        a0 += v.x * wv.x; a1 += v.y * wv.y;
        a2 += v.z * wv.z; a3 += v.w * wv.w;
      }
    }
    float s1 = a0 + a1 + a2 + a3;
    float s2 = a0 * a0 + a1 * a1 + a2 * a2 + a3 * a3;
    #pragma unroll
    for (int d = 1; d < 64; d <<= 1) { s1 += __shfl_xor(s1, d); s2 += __shfl_xor(s2, d); }
    const float mu = s1 * (1.0f / 256.0f);
    const float var = s2 * (1.0f / 256.0f) - mu * mu;
    const float rs = rsqrtf(var + 1e-5f);
    float4 lg4 = *(const float4*)(lng + c0);
    float4 lb4 = *(const float4*)(lnb + c0);
    ushort4 o;
    o.x = f2b(gelu_exact((a0 - mu) * rs * lg4.x + lb4.x));
    o.y = f2b(gelu_exact((a1 - mu) * rs * lg4.y + lb4.y));
    o.z = f2b(gelu_exact((a2 - mu) * rs * lg4.z + lb4.z));
    o.w = f2b(gelu_exact((a3 - mu) * rs * lg4.w + lb4.w));
    *(ushort4*)(x1 + (size_t)p * 256 + c0) = o;
  }
}

// ============ shared 64x64 MFMA GEMM body (K=256), bf16 out ============
template<int AF32>
__device__ __forceinline__ void gemm64_body(
    const void* __restrict__ Asrc, const u16* __restrict__ Brows,
    const float* __restrict__ bias, u16* __restrict__ Cout,
    int Ntot, int m0, int n0, char* As, char* Bs, int t)
{
  if (AF32) {
    const int r = t >> 2;                 // 4 threads per 256-f32 row
    const float4* src = (const float4*)((const float*)Asrc + (size_t)(m0 + r) * 256);
    #pragma unroll
    for (int i = 0; i < 16; ++i) {        // 16 float4 per thread = 64 f4/row
      const int f4 = (t & 3) + i * 4;
      float4 v = src[f4];
      uint2 pk;
      pk.x = (u32)f2b(v.x) | ((u32)f2b(v.y) << 16);
      pk.y = (u32)f2b(v.z) | ((u32)f2b(v.w) << 16);
      *(uint2*)(As + swz(r, f4 >> 1) + (f4 & 1) * 8) = pk;
    }
  } else {
    const int r = t >> 2, c0 = t & 3;
    const u16* Ag = (const u16*)Asrc + (size_t)(m0 + r) * 256;
    #pragma unroll
    for (int i = 0; i < 8; ++i) {
      const int b = c0 + i * 4;
      *(uint4*)(As + swz(r, b)) = *(const uint4*)(Ag + b * 8);
    }
  }
  {
    const int r = t >> 2, c0 = t & 3;
    const int nrow = n0 + r;
    const u16* Bg = Brows + (size_t)nrow * 256;
    const bool bok = nrow < Ntot;
    #pragma unroll
    for (int i = 0; i < 8; ++i) {
      const int b = c0 + i * 4;
      uint4 bv = make_uint4(0u, 0u, 0u, 0u);
      if (bok) bv = *(const uint4*)(Bg + b * 8);
      *(uint4*)(Bs + swz(r, b)) = bv;
    }
  }
  __syncthreads();
  const int l = t & 63, w = t >> 6;
  const int wm = (w >> 1) << 5, wn = (w & 1) << 5;
  const int lr = l & 15, lk = l >> 4;
  const int ra0 = wm + lr, ra1 = wm + 16 + lr;
  const int rb0 = wn + lr, rb1 = wn + 16 + lr;
  f32x4 acc00 = {}, acc01 = {}, acc10 = {}, acc11 = {};
  #pragma unroll
  for (int ks = 0; ks < 8; ++ks) {
    const int bb = ks * 4 + lk;
    short8 a0 = *(const short8*)(As + swz(ra0, bb));
    short8 a1 = *(const short8*)(As + swz(ra1, bb));
    short8 b0 = *(const short8*)(Bs + swz(rb0, bb));
    short8 b1 = *(const short8*)(Bs + swz(rb1, bb));
    acc00 = __builtin_amdgcn_mfma_f32_16x16x32_bf16(a0, b0, acc00, 0, 0, 0);
    acc01 = __builtin_amdgcn_mfma_f32_16x16x32_bf16(a0, b1, acc01, 0, 0, 0);
    acc10 = __builtin_amdgcn_mfma_f32_16x16x32_bf16(a1, b0, acc10, 0, 0, 0);
    acc11 = __builtin_amdgcn_mfma_f32_16x16x32_bf16(a1, b1, acc11, 0, 0, 0);
  }
  const f32x4 accs[2][2] = {{acc00, acc01}, {acc10, acc11}};
  #pragma unroll
  for (int mi = 0; mi < 2; ++mi)
    #pragma unroll
    for (int ni = 0; ni < 2; ++ni) {
      const int col = n0 + wn + ni * 16 + lr;
      if (col < Ntot) {
        const float bv = bias[col];
        #pragma unroll
        for (int r4 = 0; r4 < 4; ++r4) {
          const int row = m0 + wm + mi * 16 + lk * 4 + r4;
          Cout[(size_t)row * Ntot + col] = f2b(accs[mi][ni][r4] + bv);
        }
      }
    }
}

// ============ D2: [xp GEMM (blocks 0..783)] + [om GEMM (784..2155)] ============
__global__ __launch_bounds__(256) void k2_kernel(
    const float* __restrict__ xf, const u16* __restrict__ x1,
    const u16* __restrict__ wT, const float* __restrict__ b_in,
    const float* __restrict__ bcat, u16* __restrict__ xp_bf,
    u16* __restrict__ omb)
{
  __shared__ u16 lds[32768];              // 64 KB: A 32K | B 32K
  char* As = (char*)lds;
  char* Bs = (char*)(lds + 16384);
  const int t = threadIdx.x;
  if (blockIdx.x < 784) {
    const int sb = xcd_swz(blockIdx.x, 784);
    const int m0 = (sb >> 2) * 64, n0 = (sb & 3) * 64;
    gemm64_body<1>(xf, wT, b_in, xp_bf, 256, m0, n0, As, Bs, t);
  } else {
    const int sb = xcd_swz((int)blockIdx.x - 784, 1372);
    const int m0 = (sb / 7) * 64, n0 = (sb % 7) * 64;
    gemm64_body<0>(x1, wT + 1024 * 256, bcat, omb, 432, m0, n0, As, Bs, t);
  }
}

// ============ D3 fused: dcnv3 gather (32 px) -> w_out+LN1+res -> fc1+gelu ->
//              fc2 -> LN2+res.  BM=32, 512 thr, 392 blocks. y never hits global.
__global__ __launch_bounds__(512) void dcn_tail_kernel(
    const u16* __restrict__ xp, const u16* __restrict__ omb,
    const u16* __restrict__ wT, const float* __restrict__ x,
    const float* __restrict__ b_out, const float* __restrict__ gamma1,
    const float* __restrict__ ln1g, const float* __restrict__ ln1b,
    const float* __restrict__ b_fc1, const float* __restrict__ b_fc2,
    const float* __restrict__ gamma2, const float* __restrict__ ln2g,
    const float* __restrict__ ln2b, float* __restrict__ out)
{
  __shared__ u16 As[32 * 256];            // 16 KB, reused: y, x2b, m1 (swizzled rows)
  __shared__ u16 lom[32 * 432];           // 27648 B
  __shared__ float redS[32][8], redQ[32][8];
  const int t = threadIdx.x;
  const int blk = xcd_swz(blockIdx.x, 392);
  const int p0 = blk * 32;

  // stage om rows (32 x 54 uint4)
  for (int i = t; i < 1728; i += 512) {
    const int row = i / 54, u = i - row * 54;
    *(uint4*)(lom + row * 432 + u * 8) =
        *(const uint4*)(omb + (size_t)(p0 + row) * 432 + u * 8);
  }
  __syncthreads();

  // ---- phase A: dcnv3 gather, 16 thr/px x 16 ch ----
  {
    const int lp = t >> 4, g = t & 15;
    const int p = p0 + lp;
    const int bb = p / HW2, hw = p - bb * HW2;
    const int h = hw / NW, w = hw - h * NW;
    const u16* off = lom + lp * 432 + g * 18;
    const u16* mk  = lom + lp * 432 + 288 + g * 9;
    float lg[9];
    float mx = -1e30f;
    #pragma unroll
    for (int k = 0; k < 9; ++k) { lg[k] = b2f(mk[k]); mx = fmaxf(mx, lg[k]); }
    float se = 0.0f;
    #pragma unroll
    for (int k = 0; k < 9; ++k) { lg[k] = __expf(lg[k] - mx); se += lg[k]; }
    const float inv = 1.0f / se;
    float a[16];
    #pragma unroll
    for (int j = 0; j < 16; ++j) a[j] = 0.f;
    const u16* gbase = xp + (size_t)bb * HW2 * 256 + g * 16;
    auto corner = [&](int cx, int cy, float wt) {
      if (cx < 0 || cx >= NW || cy < 0 || cy >= NH) return;
      const u16* vp = gbase + (size_t)(cy * NW + cx) * 256;
      uint4 v0 = *(const uint4*)vp;
      uint4 v1 = *(const uint4*)(vp + 8);
      const u32 wv[8] = {v0.x, v0.y, v0.z, v0.w, v1.x, v1.y, v1.z, v1.w};
      #pragma unroll
      for (int j = 0; j < 8; ++j) {
        union { u32 u; float f; } lo, hi;
        lo.u = wv[j] << 16; hi.u = wv[j] & 0xffff0000u;
        a[2 * j]     += wt * lo.f;
        a[2 * j + 1] += wt * hi.f;
      }
    };
    #pragma unroll
    for (int k = 0; k < 9; ++k) {
      const float px = (float)(w + (k % 3) - 1) + b2f(off[2 * k]);
      const float py = (float)(h + (k / 3) - 1) + b2f(off[2 * k + 1]);
      const float fx = floorf(px), fy = floorf(py);
      const int ix = (int)fx, iy = (int)fy;
      const float ax = px - fx, ay = py - fy;
      const float mwt = lg[k] * inv;
      corner(ix,     iy,     (1.0f - ax) * (1.0f - ay) * mwt);
      corner(ix + 1, iy,     ax * (1.0f - ay) * mwt);
      corner(ix,     iy + 1, (1.0f - ax) * ay * mwt);
      corner(ix + 1, iy + 1, ax * ay * mwt);
    }
    u16 tmp[16];
    #pragma unroll
    for (int j = 0; j < 16; ++j) tmp[j] = f2b(a[j]);
    const int u0 = g * 2;                 // 16B-unit indices u0, u0+1 of row lp
    *(uint4*)((char*)As + lp * 512 + (((u0    ) ^ (lp & 7)) << 4)) = *(const uint4*)(tmp);
    *(uint4*)((char*)As + lp * 512 + (((u0 + 1) ^ (lp & 7)) << 4)) = *(const uint4*)(tmp + 8);
  }
  __syncthreads();

  // ---- phase B: tail chain, BM=32, 8 waves x 32 cols ----
  const int l = t & 63, w8 = t >> 6;      // wave covers cols w8*32 .. +31
  const int lr = l & 15, lk = l >> 4;
  const int colb = w8 * 32 + lr;          // thread's cols: colb, colb+16
  f32x4 acc[2][2];
  auto do_gemm = [&](const u16* Bt) {
    #pragma unroll
    for (int mi = 0; mi < 2; ++mi)
      #pragma unroll
      for (int ni = 0; ni < 2; ++ni) acc[mi][ni] = (f32x4){0.f, 0.f, 0.f, 0.f};
    const u16* Bbase = Bt + (size_t)(w8 * 32 + lr) * 256 + lk * 8;
    #pragma unroll
    for (int ks = 0; ks < 8; ++ks) {
      short8 a0 = *(const short8*)((char*)As + swz(lr,      ks * 4 + lk));
      short8 a1 = *(const short8*)((char*)As + swz(16 + lr, ks * 4 + lk));
      #pragma unroll
      for (int ni = 0; ni < 2; ++ni) {
        short8 b = *(const short8*)(Bbase + ni * 16 * 256 + ks * 32);
        acc[0][ni] = __builtin_amdgcn_mfma_f32_16x16x32_bf16(a0, b, acc[0][ni], 0, 0, 0);
        acc[1][ni] = __builtin_amdgcn_mfma_f32_16x16x32_bf16(a1, b, acc[1][ni], 0, 0, 0);
      }
    }
  };
  auto lds_write_b16 = [&](int row, int col, u16 v) {
    *(u16*)((char*)As + row * 512 + (((col >> 3) ^ (row & 7)) << 4) + (col & 7) * 2) = v;
  };
  auto ln_reduce = [&](const float bv[2]) {
    float s1[2][4], s2[2][4];
    #pragma unroll
    for (int mi = 0; mi < 2; ++mi)
      #pragma unroll
      for (int r4 = 0; r4 < 4; ++r4) {
        float s = 0.f, q = 0.f;
        #pragma unroll
        for (int ni = 0; ni < 2; ++ni) {
          const float v = acc[mi][ni][r4] + bv[ni];
          s += v; q += v * v;
        }
        s1[mi][r4] = s; s2[mi][r4] = q;
      }
    #pragma unroll
    for (int d = 1; d < 16; d <<= 1)
      #pragma unroll
      for (int mi = 0; mi < 2; ++mi)
        #pragma unroll
        for (int r4 = 0; r4 < 4; ++r4) {
          s1[mi][r4] += __shfl_xor(s1[mi][r4], d);
          s2[mi][r4] += __shfl_xor(s2[mi][r4], d);
        }
    if (lr == 0) {
      #pragma unroll
      for (int mi = 0; mi < 2; ++mi)
        #pragma unroll
        for (int r4 = 0; r4 < 4; ++r4) {
          const int rl = mi * 16 + lk * 4 + r4;
          redS[rl][w8] = s1[mi][r4];
          redQ[rl][w8] = s2[mi][r4];
        }
    }
    __syncthreads();
  };
  auto row_stats = [&](int rl, float& mu, float& rs) {
    float S = 0.f, Q = 0.f;
    #pragma unroll
    for (int j = 0; j < 8; ++j) { S += redS[rl][j]; Q += redQ[rl][j]; }
    mu = S * (1.0f / 256.0f);
    const float var = Q * (1.0f / 256.0f) - mu * mu;
    rs = rsqrtf(var + 1e-5f);
  };

  // ---- GEMM1: y @ w_out ----
  do_gemm(wT + 256 * 256);
  float bv1[2] = {b_out[colb], b_out[colb + 16]};
  ln_reduce(bv1);                         // barrier inside (fences As reads)

  // ---- LN1 + residual -> x2 (regs) + x2b (LDS) ----
  float x2r[2][4][2];
  {
    const float gm[2]  = {gamma1[colb], gamma1[colb + 16]};
    const float lgv[2] = {ln1g[colb],   ln1g[colb + 16]};
    const float lbv[2] = {ln1b[colb],   ln1b[colb + 16]};
    #pragma unroll
    for (int mi = 0; mi < 2; ++mi)
      #pragma unroll
      for (int r4 = 0; r4 < 4; ++r4) {
        const int rl = mi * 16 + lk * 4 + r4;
        float mu, rs; row_stats(rl, mu, rs);
        const int row = p0 + rl;
        #pragma unroll
        for (int ni = 0; ni < 2; ++ni) {
          const float v = acc[mi][ni][r4] + bv1[ni];
          const float o = x[(size_t)row * 256 + colb + ni * 16]
                        + gm[ni] * ((v - mu) * rs * lgv[ni] + lbv[ni]);
          x2r[mi][r4][ni] = o;
          lds_write_b16(rl, colb + ni * 16, f2b(o));
        }
      }
  }
  __syncthreads();

  // ---- GEMM2: x2 @ w_fc1, gelu -> m1 (LDS) ----
  do_gemm(wT + 512 * 256);
  float m1v[2][4][2];
  const float bf1[2] = {b_fc1[colb], b_fc1[colb + 16]};
  #pragma unroll
  for (int mi = 0; mi < 2; ++mi)
    #pragma unroll
    for (int r4 = 0; r4 < 4; ++r4)
      #pragma unroll
      for (int ni = 0; ni < 2; ++ni)
        m1v[mi][r4][ni] = gelu_exact(acc[mi][ni][r4] + bf1[ni]);
  __syncthreads();                        // all GEMM2 As-reads done
  #pragma unroll
  for (int mi = 0; mi < 2; ++mi)
    #pragma unroll
    for (int r4 = 0; r4 < 4; ++r4) {
      const int rl = mi * 16 + lk * 4 + r4;
      #pragma unroll
      for (int ni = 0; ni < 2; ++ni)
        lds_write_b16(rl, colb + ni * 16, f2b(m1v[mi][r4][ni]));
    }
  __syncthreads();

  // ---- GEMM3: m1 @ w_fc2, LN2 + residual -> out ----
  do_gemm(wT + 768 * 256);
  float bv3[2] = {b_fc2[colb], b_fc2[colb + 16]};
  ln_reduce(bv3);
  {
    const float gm[2]  = {gamma2[colb], gamma2[colb + 16]};
    const float lgv[2] = {ln2g[colb],   ln2g[colb + 16]};
    const float lbv[2] = {ln2b[colb],   ln2b[colb + 16]};
    #pragma unroll
    for (int mi = 0; mi < 2; ++mi)
      #pragma unroll
      for (int r4 = 0; r4 < 4; ++r4) {
        const int rl = mi * 16 + lk * 4 + r4;
        float mu, rs; row_stats(rl, mu, rs);
        const int row = p0 + rl;
        #pragma unroll
        for (int ni = 0; ni < 2; ++ni) {
          const float v = acc[mi][ni][r4] + bv3[ni];
          out[(size_t)row * 256 + colb + ni * 16] =
              x2r[mi][r4][ni] + gm[ni] * ((v - mu) * rs * lgv[ni] + lbv[ni]);
        }
      }
  }
}

// ============ workspace layout (bytes) ============
static constexpr size_t OFF_WT  = 0;                    // 1456*256*2 = 745,472
static constexpr size_t OFF_BC  = 745472;               // 432*4, padded to 2048
static constexpr size_t OFF_XP  = 747520;               // xp bf16 (6,422,528)
static constexpr size_t OFF_X1  = 7170048;              // x1 bf16 (6,422,528)
static constexpr size_t OFF_OMB = 13592576;             // om bf16 NPIX*432*2 = 10,838,016
// total: 24,430,592 bytes

extern "C" void kernel_launch(void* const* d_in, const int* in_sizes, int n_in,
                              void* d_out, int out_size, void* d_ws, size_t ws_size,
                              hipStream_t stream)
{
  const float* x      = (const float*)d_in[0];
  const float* w_in   = (const float*)d_in[1];
  const float* b_in   = (const float*)d_in[2];
  const float* w_dw   = (const float*)d_in[3];
  const float* b_dw   = (const float*)d_in[4];
  const float* ln_dw_g= (const float*)d_in[5];
  const float* ln_dw_b= (const float*)d_in[6];
  const float* w_off  = (const float*)d_in[7];
  const float* b_off  = (const float*)d_in[8];
  const float* w_mask = (const float*)d_in[9];
  const float* b_mask = (const float*)d_in[10];
  const float* w_out  = (const float*)d_in[11];
  const float* b_out  = (const float*)d_in[12];
  const float* ln1_g  = (const float*)d_in[13];
  const float* ln1_b  = (const float*)d_in[14];
  const float* w_fc1  = (const float*)d_in[15];
  const float* b_fc1  = (const float*)d_in[16];
  const float* w_fc2  = (const float*)d_in[17];
  const float* b_fc2  = (const float*)d_in[18];
  const float* ln2_g  = (const float*)d_in[19];
  const float* ln2_b  = (const float*)d_in[20];
  const float* gamma1 = (const float*)d_in[21];
  const float* gamma2 = (const float*)d_in[22];
  float* out = (float*)d_out;

  char* ws = (char*)d_ws;
  u16*   wT    = (u16*)  (ws + OFF_WT);
  float* bcat  = (float*)(ws + OFF_BC);
  u16*   xp_bf = (u16*)  (ws + OFF_XP);
  u16*   x1    = (u16*)  (ws + OFF_X1);
  u16*   omb   = (u16*)  (ws + OFF_OMB);

  // D1: [prep weights + bias] || [dwconv+LN+GELU -> x1]
  k1_kernel<<<dim3(1457 + 3136), 256, 0, stream>>>(
      w_in, w_out, w_fc1, w_fc2, w_off, w_mask, b_off, b_mask, wT, bcat,
      x, w_dw, b_dw, ln_dw_g, ln_dw_b, x1);
  // D2: [xp = bf16(x @ w_in + b_in)] || [om = bf16(x1 @ [w_off|w_mask] + bcat)]
  k2_kernel<<<dim3(784 + 1372), 256, 0, stream>>>(
      x, x1, wT, b_in, bcat, xp_bf, omb);
  // D3: fused dcnv3 gather + full tail -> out (y stays in LDS)
  dcn_tail_kernel<<<dim3(392), 512, 0, stream>>>(
      xp_bf, omb, wT, x, b_out, gamma1, ln1_g, ln1_b, b_fc1, b_fc2,
      gamma2, ln2_g, ln2_b, out);
}